// Round 7
// baseline (430.267 us; speedup 1.0000x reference)
//
#include <hip/hip_runtime.h>
#include <hip/hip_bf16.h>
#include <stdint.h>

#define T_TOK 32768
#define NEXP 8
#define MT_MAX 264          // 128-row granules incl. per-expert padding (pad=128)
#define MCAP (MT_MAX * 128) // 33792
#define RBLK 512            // routing block threads
#define NBLK (T_TOK / RBLK) // routing blocks = 64

typedef short s16x8 __attribute__((ext_vector_type(8)));
typedef float f32x4 __attribute__((ext_vector_type(4)));

__device__ __forceinline__ void gload_lds16(const void* g, void* l) {
  typedef const __attribute__((address_space(1))) unsigned int gu32;
  typedef __attribute__((address_space(3))) unsigned int lu32;
  __builtin_amdgcn_global_load_lds((gu32*)(unsigned long long)g,
                                   (lu32*)(unsigned int)(unsigned long long)l,
                                   16, 0, 0);
}

__device__ __forceinline__ unsigned int pack2bf(float a, float b) {
  union { __hip_bfloat16 h[2]; unsigned int u; } p;
  p.h[0] = __float2bfloat16(a);
  p.h[1] = __float2bfloat16(b);
  return p.u;
}

// ---------------- routing (atomic-free at device scope) ----------------

__global__ void k_init(int* __restrict__ perm) {
  int i = blockIdx.x * blockDim.x + threadIdx.x;
  if (i < MCAP) perm[i] = -1;
}

__global__ void k_hist(const float* __restrict__ in, int* __restrict__ ids,
                       int* __restrict__ blockHist) {
  __shared__ int h[NEXP];
  int tid = threadIdx.x;
  if (tid < NEXP) h[tid] = 0;
  __syncthreads();
  int t = blockIdx.x * RBLK + tid;
  const float* p = in + (size_t)t * 136 + 128;
  float bv = p[0]; int best = 0;
#pragma unroll
  for (int j = 1; j < 8; ++j) { float v = p[j]; if (v > bv) { bv = v; best = j; } }
  ids[t] = best;
  atomicAdd(&h[best], 1);   // LDS atomic — cheap
  __syncthreads();
  if (tid < NEXP) blockHist[blockIdx.x * NEXP + tid] = h[tid];
}

// single block: per-expert exclusive prefix over blocks + 128-padded expert offsets
__global__ void k_scan(const int* __restrict__ blockHist, int* __restrict__ blockBase,
                       int* __restrict__ meta) {
  __shared__ int cnt[NEXP];
  int e = threadIdx.x;
  if (e < NEXP) {
    int acc = 0;
    for (int b = 0; b < NBLK; ++b) {
      blockBase[b * NEXP + e] = acc;
      acc += blockHist[b * NEXP + e];
    }
    cnt[e] = acc;
  }
  __syncthreads();
  if (e == 0) {
    int acc = 0;
    for (int i = 0; i < NEXP; ++i) {
      meta[16 + i] = acc;
      acc += ((cnt[i] + 127) / 128) * 128;   // pad to 128-row slabs
    }
    meta[16 + NEXP] = acc;
  }
  __syncthreads();
  if (e < NEXP) {
    int o = meta[16 + e];
    for (int b = 0; b < NBLK; ++b) blockBase[b * NEXP + e] += o;
  }
}

__global__ void k_assign(const int* __restrict__ ids, const int* __restrict__ blockBase,
                         int* __restrict__ rowOf, int* __restrict__ perm) {
  __shared__ int cur[NEXP];
  int tid = threadIdx.x;
  if (tid < NEXP) cur[tid] = blockBase[blockIdx.x * NEXP + tid];
  __syncthreads();
  int t = blockIdx.x * RBLK + tid;
  int e = ids[t];
  int row = atomicAdd(&cur[e], 1);   // LDS atomic — cheap
  rowOf[t] = row;
  perm[row] = t;
}

__global__ void k_gather(const float* __restrict__ in, const int* __restrict__ rowOf,
                         __hip_bfloat16* __restrict__ Xs) {
  int g = blockIdx.x * blockDim.x + threadIdx.x;
  if (g >= T_TOK * 32) return;
  int t = g >> 5, c = g & 31;
  int row = rowOf[t];
  f32x4 v = *(const f32x4*)(in + (size_t)t * 136 + c * 4);
  union { unsigned short u[4]; unsigned long long ll; } pk;
#pragma unroll
  for (int j = 0; j < 4; ++j) {
    __hip_bfloat16 h = __float2bfloat16(v[j]);
    pk.u[j] = *(unsigned short*)&h;
  }
  *(unsigned long long*)(Xs + (size_t)row * 128 + c * 4) = pk.ll;
}

__global__ void k_padfill(const int* __restrict__ meta, const int* __restrict__ perm,
                          unsigned int* __restrict__ Xs32) {
  int row = blockIdx.x * blockDim.x + threadIdx.x;
  if (row >= MCAP) return;
  int mtotal = meta[16 + NEXP];
  if (row < mtotal && perm[row] < 0) {
    unsigned int* p = Xs32 + (size_t)row * 64;
#pragma unroll 4
    for (int c = 0; c < 64; ++c) p[c] = 0;
  }
}

__global__ void k_w2bf(const float* __restrict__ s, unsigned long long* __restrict__ d, int n4) {
  int i = blockIdx.x * blockDim.x + threadIdx.x;
  if (i >= n4) return;
  f32x4 v = ((const f32x4*)s)[i];
  union { unsigned short u[4]; unsigned long long ll; } pk;
#pragma unroll
  for (int j = 0; j < 4; ++j) {
    __hip_bfloat16 h = __float2bfloat16(v[j]);
    pk.u[j] = *(unsigned short*)&h;
  }
  d[i] = pk.ll;
}

// ---------------- fused persistent MLP (spill-free: two N-half passes/layer) --
// Block = 512 threads (8 waves) owns a 128-token slab for ALL 7 layers.
// Activations live in LDS [128][K] bf16, XOR chunk-swizzled. Each layer is
// computed in PASSES of 32 output columns per wave: acc f32x4[8][2] (64 regs)
// + W reg-dbuf (32 regs); pass results held packed-bf16 (32 regs) until one
// barrier, then written back to the same LDS buffer. Peak ~160 regs -> no
// scratch spill (round-6 failure mode: 134 MB/dispatch scratch writes).
// W[e] streams global->VGPR from XCD-local L2 (bid&7 = e -> XCD affinity).

// one 128xKL * KLx32 pass; result (bias+optional relu) packed into held[8][2][2]
template <int KL, bool RELU>
__device__ __forceinline__ void gemm_pass(
    const __hip_bfloat16* __restrict__ Wl,   // expert's W base, layout [NL][KL]
    const float* __restrict__ bl,            // expert's bias base
    const __hip_bfloat16* xls, int n0p, int lane,
    unsigned int (&held)[8][2][2]) {
  constexpr int NS = KL / 64;                // K-steps (even: 2 or 8)

  f32x4 acc[8][2];
#pragma unroll
  for (int i = 0; i < 8; ++i)
#pragma unroll
    for (int j = 0; j < 2; ++j) {
      acc[i][j][0] = 0.f; acc[i][j][1] = 0.f; acc[i][j][2] = 0.f; acc[i][j][3] = 0.f;
    }

  const __hip_bfloat16* wbase =
      Wl + (size_t)(n0p + (lane & 15)) * KL + ((lane >> 4) << 3);

  s16x8 wA[2][2], wB[2][2];
#pragma unroll
  for (int j = 0; j < 2; ++j)
#pragma unroll
    for (int h = 0; h < 2; ++h)
      wA[j][h] = *(const s16x8*)(wbase + j * 16 * KL + h * 32);

  auto step = [&](int s, s16x8 (&wu)[2][2], s16x8 (&wp)[2][2]) {
    if (s + 1 < NS) {          // prefetch next K-step's W before the MFMAs
#pragma unroll
      for (int j = 0; j < 2; ++j)
#pragma unroll
        for (int h = 0; h < 2; ++h)
          wp[j][h] = *(const s16x8*)(wbase + j * 16 * KL + (s + 1) * 64 + h * 32);
    }
#pragma unroll
    for (int h = 0; h < 2; ++h) {
      int cj = s * 8 + h * 4 + (lane >> 4);  // 16B chunk index within row
#pragma unroll
      for (int i = 0; i < 8; ++i) {
        int ar = i * 16 + (lane & 15);
        int js = cj ^ (ar & 7);
        s16x8 a = *(const s16x8*)(xls + ar * KL + js * 8);
#pragma unroll
        for (int j = 0; j < 2; ++j)
          acc[i][j] = __builtin_amdgcn_mfma_f32_16x16x32_bf16(a, wu[j][h], acc[i][j], 0, 0, 0);
      }
    }
  };

#pragma unroll
  for (int s = 0; s < NS; s += 2) {
    step(s, wA, wB);
    step(s + 1, wB, wA);
  }

#pragma unroll
  for (int j = 0; j < 2; ++j) {
    float bv = bl[n0p + j * 16 + (lane & 15)];
#pragma unroll
    for (int i = 0; i < 8; ++i) {
      float v0 = acc[i][j][0] + bv, v1 = acc[i][j][1] + bv;
      float v2 = acc[i][j][2] + bv, v3 = acc[i][j][3] + bv;
      if (RELU) {
        v0 = fmaxf(v0, 0.f); v1 = fmaxf(v1, 0.f);
        v2 = fmaxf(v2, 0.f); v3 = fmaxf(v3, 0.f);
      }
      held[i][j][0] = pack2bf(v0, v1);
      held[i][j][1] = pack2bf(v2, v3);
    }
  }
}

template <int KL, int NL, bool RELU>
__device__ __forceinline__ void run_layer(
    const __hip_bfloat16* __restrict__ Wl, const float* __restrict__ bl,
    __hip_bfloat16* xls, int lane, int wave) {
  constexpr int WTN = NL / 8;          // 64 (NL=512) or 32 (NL=256)
  constexpr int NPASS = WTN / 32;      // 2 or 1
  unsigned int held[NPASS][8][2][2];

#pragma unroll
  for (int p = 0; p < NPASS; ++p)
    gemm_pass<KL, RELU>(Wl, bl, xls, wave * WTN + p * 32, lane, held[p]);

  __syncthreads();   // all waves done reading xls
  unsigned short* x16 = (unsigned short*)xls;
#pragma unroll
  for (int p = 0; p < NPASS; ++p) {
#pragma unroll
    for (int j = 0; j < 2; ++j) {
      int nc = wave * WTN + p * 32 + j * 16 + (lane & 15);
#pragma unroll
      for (int i = 0; i < 8; ++i) {
#pragma unroll
        for (int r2 = 0; r2 < 2; ++r2) {
          unsigned int u = held[p][i][j][r2];
          int row0 = i * 16 + ((lane >> 4) << 2) + r2 * 2;
          int row1 = row0 + 1;
          x16[row0 * NL + (((nc >> 3) ^ (row0 & 7)) << 3) + (nc & 7)] = (unsigned short)(u & 0xffff);
          x16[row1 * NL + (((nc >> 3) ^ (row1 & 7)) << 3) + (nc & 7)] = (unsigned short)(u >> 16);
        }
      }
    }
  }
  __syncthreads();
}

// layer 7: K=256 -> N=32, per-wave M-split (wave w owns rows w*16..w*16+15),
// f32 output scattered to out[tok][32] via perm.
__device__ __forceinline__ void run_layer7(
    const __hip_bfloat16* __restrict__ W7, const float* __restrict__ b7,
    const __hip_bfloat16* xls, float* __restrict__ out,
    const int* __restrict__ perm, int m0, int lane, int wave) {
  constexpr int KL = 256;
  f32x4 acc[2];
#pragma unroll
  for (int j = 0; j < 2; ++j) { acc[j][0]=0.f; acc[j][1]=0.f; acc[j][2]=0.f; acc[j][3]=0.f; }
  const __hip_bfloat16* wbase = W7 + (size_t)(lane & 15) * KL + ((lane >> 4) << 3);
  int ar = wave * 16 + (lane & 15);
#pragma unroll
  for (int s = 0; s < 4; ++s) {
#pragma unroll
    for (int h = 0; h < 2; ++h) {
      int kbase = s * 64 + h * 32;
      int cj = (kbase >> 3) + (lane >> 4);
      int js = cj ^ (ar & 7);
      s16x8 a = *(const s16x8*)(xls + ar * KL + js * 8);
#pragma unroll
      for (int j = 0; j < 2; ++j) {
        s16x8 w = *(const s16x8*)(wbase + j * 16 * KL + kbase);
        acc[j] = __builtin_amdgcn_mfma_f32_16x16x32_bf16(a, w, acc[j], 0, 0, 0);
      }
    }
  }
#pragma unroll
  for (int j = 0; j < 2; ++j) {
    int nc = j * 16 + (lane & 15);
    float bv = b7[nc];
#pragma unroll
    for (int r = 0; r < 4; ++r) {
      int mr = wave * 16 + ((lane >> 4) << 2) + r;
      int tok = perm[m0 + mr];
      if (tok >= 0) out[(size_t)tok * 32 + nc] = acc[j][r] + bv;
    }
  }
}

__global__ __launch_bounds__(512, 2) void k_fused(
    const __hip_bfloat16* __restrict__ Xs,
    const __hip_bfloat16* __restrict__ W1, const __hip_bfloat16* __restrict__ W2,
    const __hip_bfloat16* __restrict__ W3, const __hip_bfloat16* __restrict__ W4,
    const __hip_bfloat16* __restrict__ W5, const __hip_bfloat16* __restrict__ W6,
    const __hip_bfloat16* __restrict__ W7,
    const float* __restrict__ B1, const float* __restrict__ B2,
    const float* __restrict__ B3, const float* __restrict__ B4,
    const float* __restrict__ B5, const float* __restrict__ B6,
    const float* __restrict__ B7,
    float* __restrict__ out,
    const int* __restrict__ meta, const int* __restrict__ perm) {
  __shared__ __hip_bfloat16 xls[128 * 512];   // 128 KB
  const int* offp = meta + 16;
  int e = blockIdx.x & 7;                     // expert -> XCD affinity
  int s = blockIdx.x >> 3;
  int m0 = offp[e] + s * 128;
  if (m0 >= offp[e + 1]) return;
  int tid = threadIdx.x, lane = tid & 63, wave = tid >> 6;

  // stage the 128x128 bf16 input slab (swizzled source, linear LDS dest)
#pragma unroll
  for (int i = 0; i < 4; ++i) {
    int c = i * 512 + tid;
    int r = c >> 4, kc = c & 15;
    int kcs = kc ^ (r & 7);
    gload_lds16(Xs + (size_t)(m0 + r) * 128 + kcs * 8, (char*)xls + c * 16);
  }
  asm volatile("s_waitcnt vmcnt(0)" ::: "memory");
  __builtin_amdgcn_s_barrier();

  run_layer<128, 512, true >(W1 + (size_t)e * 512 * 128, B1 + e * 512, xls, lane, wave);
  run_layer<512, 512, true >(W2 + (size_t)e * 512 * 512, B2 + e * 512, xls, lane, wave);
  run_layer<512, 512, false>(W3 + (size_t)e * 512 * 512, B3 + e * 512, xls, lane, wave);
  run_layer<512, 512, true >(W4 + (size_t)e * 512 * 512, B4 + e * 512, xls, lane, wave);
  run_layer<512, 512, true >(W5 + (size_t)e * 512 * 512, B5 + e * 512, xls, lane, wave);
  run_layer<512, 256, false>(W6 + (size_t)e * 256 * 512, B6 + e * 256, xls, lane, wave);
  run_layer7(W7 + (size_t)e * 32 * 256, B7 + e * 32, xls, out, perm, m0, lane, wave);
}

// ---------------- host ----------------

extern "C" void kernel_launch(void* const* d_in, const int* in_sizes, int n_in,
                              void* d_out, int out_size, void* d_ws, size_t ws_size,
                              hipStream_t stream) {
  const float* input = (const float*)d_in[0];
  const float* Wf[7]; const float* Bf[7];
  for (int i = 0; i < 7; ++i) { Wf[i] = (const float*)d_in[1 + 2 * i]; Bf[i] = (const float*)d_in[2 + 2 * i]; }
  float* out = (float*)d_out;

  static const int NN[7] = {512, 512, 512, 512, 512, 256, 32};
  static const int KK[7] = {128, 512, 512, 512, 512, 512, 256};

  char* ws = (char*)d_ws;
  size_t off = 0;
  auto carve = [&](size_t bytes) {
    void* p = ws + off;
    off = (off + bytes + 255) & ~(size_t)255;
    return p;
  };
  int* meta      = (int*)carve(128);                    // offp at meta[16..24]
  int* ids       = (int*)carve(sizeof(int) * T_TOK);
  int* rowOf     = (int*)carve(sizeof(int) * T_TOK);
  int* perm      = (int*)carve(sizeof(int) * MCAP);
  int* blockHist = (int*)carve(sizeof(int) * NBLK * NEXP);
  int* blockBase = (int*)carve(sizeof(int) * NBLK * NEXP);
  __hip_bfloat16* Xs = (__hip_bfloat16*)carve((size_t)MCAP * 128 * 2);
  __hip_bfloat16* Wb[7];
  for (int i = 0; i < 7; ++i) Wb[i] = (__hip_bfloat16*)carve((size_t)NEXP * NN[i] * KK[i] * 2);

  k_init<<<dim3((MCAP + 255) / 256), 256, 0, stream>>>(perm);
  for (int i = 0; i < 7; ++i) {
    int n4 = NEXP * NN[i] * KK[i] / 4;
    k_w2bf<<<dim3((n4 + 255) / 256), 256, 0, stream>>>(Wf[i], (unsigned long long*)Wb[i], n4);
  }
  k_hist<<<dim3(NBLK), RBLK, 0, stream>>>(input, ids, blockHist);
  k_scan<<<dim3(1), 64, 0, stream>>>(blockHist, blockBase, meta);
  k_assign<<<dim3(NBLK), RBLK, 0, stream>>>(ids, blockBase, rowOf, perm);
  k_gather<<<dim3(T_TOK * 32 / 256), 256, 0, stream>>>(input, rowOf, Xs);
  k_padfill<<<dim3((MCAP + 255) / 256), 256, 0, stream>>>(meta, perm, (unsigned int*)Xs);

  // grid = 8 experts x 256 slab slots (handles any skew up to all-one-expert);
  // inactive slots early-exit. bid&7 = expert -> XCD affinity.
  k_fused<<<dim3(8 * 256), 512, 0, stream>>>(
      Xs, Wb[0], Wb[1], Wb[2], Wb[3], Wb[4], Wb[5], Wb[6],
      Bf[0], Bf[1], Bf[2], Bf[3], Bf[4], Bf[5], Bf[6],
      out, meta, perm);
}

// Round 8
// 429.657 us; speedup vs baseline: 1.0014x; 1.0014x over previous
//
#include <hip/hip_runtime.h>
#include <hip/hip_bf16.h>
#include <stdint.h>

#define T_TOK 32768
#define NEXP 8
#define MT_MAX 264          // 128-row granules incl. per-expert padding (pad=128)
#define MCAP (MT_MAX * 128) // 33792
#define RBLK 512            // routing block threads
#define NBLK (T_TOK / RBLK) // routing blocks = 64
#define SLOTS 64            // slab slots per expert (8192 tokens; ~68 sigma)

typedef short s16x8 __attribute__((ext_vector_type(8)));
typedef float f32x4 __attribute__((ext_vector_type(4)));

__device__ __forceinline__ void gload_lds16(const void* g, void* l) {
  typedef const __attribute__((address_space(1))) unsigned int gu32;
  typedef __attribute__((address_space(3))) unsigned int lu32;
  __builtin_amdgcn_global_load_lds((gu32*)(unsigned long long)g,
                                   (lu32*)(unsigned int)(unsigned long long)l,
                                   16, 0, 0);
}

__device__ __forceinline__ unsigned int pack2bf(float a, float b) {
  union { __hip_bfloat16 h[2]; unsigned int u; } p;
  p.h[0] = __float2bfloat16(a);
  p.h[1] = __float2bfloat16(b);
  return p.u;
}

// ---------------- routing (atomic-free at device scope) ----------------

__global__ void k_init(int* __restrict__ perm) {
  int i = blockIdx.x * blockDim.x + threadIdx.x;
  if (i < MCAP) perm[i] = -1;
}

__global__ void k_hist(const float* __restrict__ in, int* __restrict__ ids,
                       int* __restrict__ blockHist) {
  __shared__ int h[NEXP];
  int tid = threadIdx.x;
  if (tid < NEXP) h[tid] = 0;
  __syncthreads();
  int t = blockIdx.x * RBLK + tid;
  const float* p = in + (size_t)t * 136 + 128;
  float bv = p[0]; int best = 0;
#pragma unroll
  for (int j = 1; j < 8; ++j) { float v = p[j]; if (v > bv) { bv = v; best = j; } }
  ids[t] = best;
  atomicAdd(&h[best], 1);   // LDS atomic — cheap
  __syncthreads();
  if (tid < NEXP) blockHist[blockIdx.x * NEXP + tid] = h[tid];
}

// single block: per-expert exclusive prefix over blocks + 128-padded expert offsets
__global__ void k_scan(const int* __restrict__ blockHist, int* __restrict__ blockBase,
                       int* __restrict__ meta) {
  __shared__ int cnt[NEXP];
  int e = threadIdx.x;
  if (e < NEXP) {
    int acc = 0;
    for (int b = 0; b < NBLK; ++b) {
      blockBase[b * NEXP + e] = acc;
      acc += blockHist[b * NEXP + e];
    }
    cnt[e] = acc;
  }
  __syncthreads();
  if (e == 0) {
    int acc = 0;
    for (int i = 0; i < NEXP; ++i) {
      meta[16 + i] = acc;
      acc += ((cnt[i] + 127) / 128) * 128;   // pad to 128-row slabs
    }
    meta[16 + NEXP] = acc;
  }
  __syncthreads();
  if (e < NEXP) {
    int o = meta[16 + e];
    for (int b = 0; b < NBLK; ++b) blockBase[b * NEXP + e] += o;
  }
}

__global__ void k_assign(const int* __restrict__ ids, const int* __restrict__ blockBase,
                         int* __restrict__ rowOf, int* __restrict__ perm) {
  __shared__ int cur[NEXP];
  int tid = threadIdx.x;
  if (tid < NEXP) cur[tid] = blockBase[blockIdx.x * NEXP + tid];
  __syncthreads();
  int t = blockIdx.x * RBLK + tid;
  int e = ids[t];
  int row = atomicAdd(&cur[e], 1);   // LDS atomic — cheap
  rowOf[t] = row;
  perm[row] = t;
}

__global__ void k_gather(const float* __restrict__ in, const int* __restrict__ rowOf,
                         __hip_bfloat16* __restrict__ Xs) {
  int g = blockIdx.x * blockDim.x + threadIdx.x;
  if (g >= T_TOK * 32) return;
  int t = g >> 5, c = g & 31;
  int row = rowOf[t];
  f32x4 v = *(const f32x4*)(in + (size_t)t * 136 + c * 4);
  union { unsigned short u[4]; unsigned long long ll; } pk;
#pragma unroll
  for (int j = 0; j < 4; ++j) {
    __hip_bfloat16 h = __float2bfloat16(v[j]);
    pk.u[j] = *(unsigned short*)&h;
  }
  *(unsigned long long*)(Xs + (size_t)row * 128 + c * 4) = pk.ll;
}

__global__ void k_padfill(const int* __restrict__ meta, const int* __restrict__ perm,
                          unsigned int* __restrict__ Xs32) {
  int row = blockIdx.x * blockDim.x + threadIdx.x;
  if (row >= MCAP) return;
  int mtotal = meta[16 + NEXP];
  if (row < mtotal && perm[row] < 0) {
    unsigned int* p = Xs32 + (size_t)row * 64;
#pragma unroll 4
    for (int c = 0; c < 64; ++c) p[c] = 0;
  }
}

__global__ void k_w2bf(const float* __restrict__ s, unsigned long long* __restrict__ d, int n4) {
  int i = blockIdx.x * blockDim.x + threadIdx.x;
  if (i >= n4) return;
  f32x4 v = ((const f32x4*)s)[i];
  union { unsigned short u[4]; unsigned long long ll; } pk;
#pragma unroll
  for (int j = 0; j < 4; ++j) {
    __hip_bfloat16 h = __float2bfloat16(v[j]);
    pk.u[j] = *(unsigned short*)&h;
  }
  d[i] = pk.ll;
}

// ---------------- fused persistent MLP (spill-free: two N-half passes/layer) --
// Block = 512 threads (8 waves) owns a 128-token slab for ALL 7 layers.
// Activations live in LDS [128][K] bf16, XOR chunk-swizzled. Each layer is
// computed in PASSES of 32 output columns per wave: acc f32x4[8][2] (64 regs)
// + W reg-dbuf (32 regs); pass results held packed-bf16 until one barrier,
// then written back to the same LDS buffer.
// ROUND 8 FIX: __launch_bounds__(512, 1) — (512,2) forced a 128-VGPR cap
// (observed VGPR_Count=128 in r6/r7) and spilled ~100 MB/dispatch to scratch.
// W[e] streams global->VGPR from XCD-local L2 (bid&7 = e -> XCD affinity).

// one 128xKL * KLx32 pass; result (bias+optional relu) packed into held[8][2][2]
template <int KL, bool RELU>
__device__ __forceinline__ void gemm_pass(
    const __hip_bfloat16* __restrict__ Wl,   // expert's W base, layout [NL][KL]
    const float* __restrict__ bl,            // expert's bias base
    const __hip_bfloat16* xls, int n0p, int lane,
    unsigned int (&held)[8][2][2]) {
  constexpr int NS = KL / 64;                // K-steps (even: 2 or 8)

  f32x4 acc[8][2];
#pragma unroll
  for (int i = 0; i < 8; ++i)
#pragma unroll
    for (int j = 0; j < 2; ++j) {
      acc[i][j][0] = 0.f; acc[i][j][1] = 0.f; acc[i][j][2] = 0.f; acc[i][j][3] = 0.f;
    }

  const __hip_bfloat16* wbase =
      Wl + (size_t)(n0p + (lane & 15)) * KL + ((lane >> 4) << 3);

  s16x8 wA[2][2], wB[2][2];
#pragma unroll
  for (int j = 0; j < 2; ++j)
#pragma unroll
    for (int h = 0; h < 2; ++h)
      wA[j][h] = *(const s16x8*)(wbase + j * 16 * KL + h * 32);

  auto step = [&](int s, s16x8 (&wu)[2][2], s16x8 (&wp)[2][2]) {
    if (s + 1 < NS) {          // prefetch next K-step's W before the MFMAs
#pragma unroll
      for (int j = 0; j < 2; ++j)
#pragma unroll
        for (int h = 0; h < 2; ++h)
          wp[j][h] = *(const s16x8*)(wbase + j * 16 * KL + (s + 1) * 64 + h * 32);
    }
#pragma unroll
    for (int h = 0; h < 2; ++h) {
      int cj = s * 8 + h * 4 + (lane >> 4);  // 16B chunk index within row
#pragma unroll
      for (int i = 0; i < 8; ++i) {
        int ar = i * 16 + (lane & 15);
        int js = cj ^ (ar & 7);
        s16x8 a = *(const s16x8*)(xls + ar * KL + js * 8);
#pragma unroll
        for (int j = 0; j < 2; ++j)
          acc[i][j] = __builtin_amdgcn_mfma_f32_16x16x32_bf16(a, wu[j][h], acc[i][j], 0, 0, 0);
      }
    }
  };

#pragma unroll
  for (int s = 0; s < NS; s += 2) {
    step(s, wA, wB);
    step(s + 1, wB, wA);
  }

#pragma unroll
  for (int j = 0; j < 2; ++j) {
    float bv = bl[n0p + j * 16 + (lane & 15)];
#pragma unroll
    for (int i = 0; i < 8; ++i) {
      float v0 = acc[i][j][0] + bv, v1 = acc[i][j][1] + bv;
      float v2 = acc[i][j][2] + bv, v3 = acc[i][j][3] + bv;
      if (RELU) {
        v0 = fmaxf(v0, 0.f); v1 = fmaxf(v1, 0.f);
        v2 = fmaxf(v2, 0.f); v3 = fmaxf(v3, 0.f);
      }
      held[i][j][0] = pack2bf(v0, v1);
      held[i][j][1] = pack2bf(v2, v3);
    }
  }
}

template <int KL, int NL, bool RELU>
__device__ __forceinline__ void run_layer(
    const __hip_bfloat16* __restrict__ Wl, const float* __restrict__ bl,
    __hip_bfloat16* xls, int lane, int wave) {
  constexpr int WTN = NL / 8;          // 64 (NL=512) or 32 (NL=256)
  constexpr int NPASS = WTN / 32;      // 2 or 1
  unsigned int held[NPASS][8][2][2];

#pragma unroll
  for (int p = 0; p < NPASS; ++p)
    gemm_pass<KL, RELU>(Wl, bl, xls, wave * WTN + p * 32, lane, held[p]);

  __syncthreads();   // all waves done reading xls
  unsigned short* x16 = (unsigned short*)xls;
#pragma unroll
  for (int p = 0; p < NPASS; ++p) {
#pragma unroll
    for (int j = 0; j < 2; ++j) {
      int nc = wave * WTN + p * 32 + j * 16 + (lane & 15);
#pragma unroll
      for (int i = 0; i < 8; ++i) {
#pragma unroll
        for (int r2 = 0; r2 < 2; ++r2) {
          unsigned int u = held[p][i][j][r2];
          int row0 = i * 16 + ((lane >> 4) << 2) + r2 * 2;
          int row1 = row0 + 1;
          x16[row0 * NL + (((nc >> 3) ^ (row0 & 7)) << 3) + (nc & 7)] = (unsigned short)(u & 0xffff);
          x16[row1 * NL + (((nc >> 3) ^ (row1 & 7)) << 3) + (nc & 7)] = (unsigned short)(u >> 16);
        }
      }
    }
  }
  __syncthreads();
}

// layer 7: K=256 -> N=32, per-wave M-split (wave w owns rows w*16..w*16+15),
// f32 output scattered to out[tok][32] via perm.
__device__ __forceinline__ void run_layer7(
    const __hip_bfloat16* __restrict__ W7, const float* __restrict__ b7,
    const __hip_bfloat16* xls, float* __restrict__ out,
    const int* __restrict__ perm, int m0, int lane, int wave) {
  constexpr int KL = 256;
  f32x4 acc[2];
#pragma unroll
  for (int j = 0; j < 2; ++j) { acc[j][0]=0.f; acc[j][1]=0.f; acc[j][2]=0.f; acc[j][3]=0.f; }
  const __hip_bfloat16* wbase = W7 + (size_t)(lane & 15) * KL + ((lane >> 4) << 3);
  int ar = wave * 16 + (lane & 15);
#pragma unroll
  for (int s = 0; s < 4; ++s) {
#pragma unroll
    for (int h = 0; h < 2; ++h) {
      int kbase = s * 64 + h * 32;
      int cj = (kbase >> 3) + (lane >> 4);
      int js = cj ^ (ar & 7);
      s16x8 a = *(const s16x8*)(xls + ar * KL + js * 8);
#pragma unroll
      for (int j = 0; j < 2; ++j) {
        s16x8 w = *(const s16x8*)(wbase + j * 16 * KL + kbase);
        acc[j] = __builtin_amdgcn_mfma_f32_16x16x32_bf16(a, w, acc[j], 0, 0, 0);
      }
    }
  }
#pragma unroll
  for (int j = 0; j < 2; ++j) {
    int nc = j * 16 + (lane & 15);
    float bv = b7[nc];
#pragma unroll
    for (int r = 0; r < 4; ++r) {
      int mr = wave * 16 + ((lane >> 4) << 2) + r;
      int tok = perm[m0 + mr];
      if (tok >= 0) out[(size_t)tok * 32 + nc] = acc[j][r] + bv;
    }
  }
}

__global__ __launch_bounds__(512, 1) void k_fused(
    const __hip_bfloat16* __restrict__ Xs,
    const __hip_bfloat16* __restrict__ W1, const __hip_bfloat16* __restrict__ W2,
    const __hip_bfloat16* __restrict__ W3, const __hip_bfloat16* __restrict__ W4,
    const __hip_bfloat16* __restrict__ W5, const __hip_bfloat16* __restrict__ W6,
    const __hip_bfloat16* __restrict__ W7,
    const float* __restrict__ B1, const float* __restrict__ B2,
    const float* __restrict__ B3, const float* __restrict__ B4,
    const float* __restrict__ B5, const float* __restrict__ B6,
    const float* __restrict__ B7,
    float* __restrict__ out,
    const int* __restrict__ meta, const int* __restrict__ perm) {
  __shared__ __hip_bfloat16 xls[128 * 512];   // 128 KB
  const int* offp = meta + 16;
  int e = blockIdx.x & 7;                     // expert -> XCD affinity
  int s = blockIdx.x >> 3;
  int m0 = offp[e] + s * 128;
  if (m0 >= offp[e + 1]) return;
  int tid = threadIdx.x, lane = tid & 63, wave = tid >> 6;

  // stage the 128x128 bf16 input slab (swizzled source, linear LDS dest)
#pragma unroll
  for (int i = 0; i < 4; ++i) {
    int c = i * 512 + tid;
    int r = c >> 4, kc = c & 15;
    int kcs = kc ^ (r & 7);
    gload_lds16(Xs + (size_t)(m0 + r) * 128 + kcs * 8, (char*)xls + c * 16);
  }
  asm volatile("s_waitcnt vmcnt(0)" ::: "memory");
  __builtin_amdgcn_s_barrier();

  run_layer<128, 512, true >(W1 + (size_t)e * 512 * 128, B1 + e * 512, xls, lane, wave);
  run_layer<512, 512, true >(W2 + (size_t)e * 512 * 512, B2 + e * 512, xls, lane, wave);
  run_layer<512, 512, false>(W3 + (size_t)e * 512 * 512, B3 + e * 512, xls, lane, wave);
  run_layer<512, 512, true >(W4 + (size_t)e * 512 * 512, B4 + e * 512, xls, lane, wave);
  run_layer<512, 512, true >(W5 + (size_t)e * 512 * 512, B5 + e * 512, xls, lane, wave);
  run_layer<512, 256, false>(W6 + (size_t)e * 256 * 512, B6 + e * 256, xls, lane, wave);
  run_layer7(W7 + (size_t)e * 32 * 256, B7 + e * 32, xls, out, perm, m0, lane, wave);
}

// ---------------- host ----------------

extern "C" void kernel_launch(void* const* d_in, const int* in_sizes, int n_in,
                              void* d_out, int out_size, void* d_ws, size_t ws_size,
                              hipStream_t stream) {
  const float* input = (const float*)d_in[0];
  const float* Wf[7]; const float* Bf[7];
  for (int i = 0; i < 7; ++i) { Wf[i] = (const float*)d_in[1 + 2 * i]; Bf[i] = (const float*)d_in[2 + 2 * i]; }
  float* out = (float*)d_out;

  static const int NN[7] = {512, 512, 512, 512, 512, 256, 32};
  static const int KK[7] = {128, 512, 512, 512, 512, 512, 256};

  char* ws = (char*)d_ws;
  size_t off = 0;
  auto carve = [&](size_t bytes) {
    void* p = ws + off;
    off = (off + bytes + 255) & ~(size_t)255;
    return p;
  };
  int* meta      = (int*)carve(128);                    // offp at meta[16..24]
  int* ids       = (int*)carve(sizeof(int) * T_TOK);
  int* rowOf     = (int*)carve(sizeof(int) * T_TOK);
  int* perm      = (int*)carve(sizeof(int) * MCAP);
  int* blockHist = (int*)carve(sizeof(int) * NBLK * NEXP);
  int* blockBase = (int*)carve(sizeof(int) * NBLK * NEXP);
  __hip_bfloat16* Xs = (__hip_bfloat16*)carve((size_t)MCAP * 128 * 2);
  __hip_bfloat16* Wb[7];
  for (int i = 0; i < 7; ++i) Wb[i] = (__hip_bfloat16*)carve((size_t)NEXP * NN[i] * KK[i] * 2);

  k_init<<<dim3((MCAP + 255) / 256), 256, 0, stream>>>(perm);
  for (int i = 0; i < 7; ++i) {
    int n4 = NEXP * NN[i] * KK[i] / 4;
    k_w2bf<<<dim3((n4 + 255) / 256), 256, 0, stream>>>(Wf[i], (unsigned long long*)Wb[i], n4);
  }
  k_hist<<<dim3(NBLK), RBLK, 0, stream>>>(input, ids, blockHist);
  k_scan<<<dim3(1), 64, 0, stream>>>(blockHist, blockBase, meta);
  k_assign<<<dim3(NBLK), RBLK, 0, stream>>>(ids, blockBase, rowOf, perm);
  k_gather<<<dim3(T_TOK * 32 / 256), 256, 0, stream>>>(input, rowOf, Xs);
  k_padfill<<<dim3((MCAP + 255) / 256), 256, 0, stream>>>(meta, perm, (unsigned int*)Xs);

  // grid = 8 experts x SLOTS slab slots; inactive slots early-exit.
  // bid&7 = expert -> XCD affinity.
  k_fused<<<dim3(8 * SLOTS), 512, 0, stream>>>(
      Xs, Wb[0], Wb[1], Wb[2], Wb[3], Wb[4], Wb[5], Wb[6],
      Bf[0], Bf[1], Bf[2], Bf[3], Bf[4], Bf[5], Bf[6],
      out, meta, perm);
}

// Round 9
// 318.676 us; speedup vs baseline: 1.3502x; 1.3483x over previous
//
#include <hip/hip_runtime.h>
#include <hip/hip_bf16.h>
#include <stdint.h>

#define T_TOK 32768
#define NEXP 8
#define MROWS 64            // slab rows per block
#define MT64_MAX 520        // 64-row granules incl. per-expert padding (pad=64)
#define MCAP (MT64_MAX * 64)
#define RBLK 512            // routing block threads
#define NBLK (T_TOK / RBLK) // routing blocks = 64
#define SLOTS 512           // slab slots per expert (covers all-one-expert)

typedef short s16x8 __attribute__((ext_vector_type(8)));
typedef float f32x4 __attribute__((ext_vector_type(4)));

__device__ __forceinline__ void gload_lds16(const void* g, void* l) {
  typedef const __attribute__((address_space(1))) unsigned int gu32;
  typedef __attribute__((address_space(3))) unsigned int lu32;
  __builtin_amdgcn_global_load_lds((gu32*)(unsigned long long)g,
                                   (lu32*)(unsigned int)(unsigned long long)l,
                                   16, 0, 0);
}

__device__ __forceinline__ unsigned short bf16bits(float v) {
  __hip_bfloat16 h = __float2bfloat16(v);
  return *(unsigned short*)&h;
}

// ---------------- routing (atomic-free at device scope) ----------------

__global__ void k_init(int* __restrict__ perm) {
  int i = blockIdx.x * blockDim.x + threadIdx.x;
  if (i < MCAP) perm[i] = -1;
}

__global__ void k_hist(const float* __restrict__ in, int* __restrict__ ids,
                       int* __restrict__ blockHist) {
  __shared__ int h[NEXP];
  int tid = threadIdx.x;
  if (tid < NEXP) h[tid] = 0;
  __syncthreads();
  int t = blockIdx.x * RBLK + tid;
  const float* p = in + (size_t)t * 136 + 128;
  float bv = p[0]; int best = 0;
#pragma unroll
  for (int j = 1; j < 8; ++j) { float v = p[j]; if (v > bv) { bv = v; best = j; } }
  ids[t] = best;
  atomicAdd(&h[best], 1);   // LDS atomic — cheap
  __syncthreads();
  if (tid < NEXP) blockHist[blockIdx.x * NEXP + tid] = h[tid];
}

// single block: per-expert exclusive prefix over blocks + 64-padded expert offsets
__global__ void k_scan(const int* __restrict__ blockHist, int* __restrict__ blockBase,
                       int* __restrict__ meta) {
  __shared__ int cnt[NEXP];
  int e = threadIdx.x;
  if (e < NEXP) {
    int acc = 0;
    for (int b = 0; b < NBLK; ++b) {
      blockBase[b * NEXP + e] = acc;
      acc += blockHist[b * NEXP + e];
    }
    cnt[e] = acc;
  }
  __syncthreads();
  if (e == 0) {
    int acc = 0;
    for (int i = 0; i < NEXP; ++i) {
      meta[16 + i] = acc;
      acc += ((cnt[i] + 63) / 64) * 64;   // pad to 64-row slabs
    }
    meta[16 + NEXP] = acc;
  }
  __syncthreads();
  if (e < NEXP) {
    int o = meta[16 + e];
    for (int b = 0; b < NBLK; ++b) blockBase[b * NEXP + e] += o;
  }
}

__global__ void k_assign(const int* __restrict__ ids, const int* __restrict__ blockBase,
                         int* __restrict__ rowOf, int* __restrict__ perm) {
  __shared__ int cur[NEXP];
  int tid = threadIdx.x;
  if (tid < NEXP) cur[tid] = blockBase[blockIdx.x * NEXP + tid];
  __syncthreads();
  int t = blockIdx.x * RBLK + tid;
  int e = ids[t];
  int row = atomicAdd(&cur[e], 1);   // LDS atomic — cheap
  rowOf[t] = row;
  perm[row] = t;
}

__global__ void k_gather(const float* __restrict__ in, const int* __restrict__ rowOf,
                         __hip_bfloat16* __restrict__ Xs) {
  int g = blockIdx.x * blockDim.x + threadIdx.x;
  if (g >= T_TOK * 32) return;
  int t = g >> 5, c = g & 31;
  int row = rowOf[t];
  f32x4 v = *(const f32x4*)(in + (size_t)t * 136 + c * 4);
  union { unsigned short u[4]; unsigned long long ll; } pk;
#pragma unroll
  for (int j = 0; j < 4; ++j) pk.u[j] = bf16bits(v[j]);
  *(unsigned long long*)(Xs + (size_t)row * 128 + c * 4) = pk.ll;
}

__global__ void k_padfill(const int* __restrict__ meta, const int* __restrict__ perm,
                          unsigned int* __restrict__ Xs32) {
  int row = blockIdx.x * blockDim.x + threadIdx.x;
  if (row >= MCAP) return;
  int mtotal = meta[16 + NEXP];
  if (row < mtotal && perm[row] < 0) {
    unsigned int* p = Xs32 + (size_t)row * 64;
#pragma unroll 4
    for (int c = 0; c < 64; ++c) p[c] = 0;
  }
}

__global__ void k_w2bf(const float* __restrict__ s, unsigned long long* __restrict__ d, int n4) {
  int i = blockIdx.x * blockDim.x + threadIdx.x;
  if (i >= n4) return;
  f32x4 v = ((const f32x4*)s)[i];
  union { unsigned short u[4]; unsigned long long ll; } pk;
#pragma unroll
  for (int j = 0; j < 4; ++j) pk.u[j] = bf16bits(v[j]);
  d[i] = pk.ll;
}

// ---------------- fused persistent MLP (ping-pong LDS, no cross-barrier regs) --
// Block = 512 threads (8 waves) owns a 64-token slab for ALL 7 layers.
// TWO 64 KB LDS activation buffers ping-pong: layer L reads bufIN, writes
// bufOUT directly in its epilogue (different buffer -> no pre-write barrier),
// then ONE barrier. No register state is held across barriers (round 6-8
// failure: spill traffic ~100 MB/dispatch). No explicit W dbuf — compiler
// pipelines the affine W loads. XOR chunk-swizzle on all LDS activations.
// W[e] streams global->VGPR from XCD-local L2 (bid&7 = e -> XCD affinity).

template <int KL, int NL, bool RELU>
__device__ __forceinline__ void run_layer(
    const __hip_bfloat16* __restrict__ Wl,   // expert's W base, layout [NL][KL]
    const float* __restrict__ bl,            // expert's bias base
    const __hip_bfloat16* __restrict__ inb,  // [64][KL] swizzled
    __hip_bfloat16* __restrict__ outb,       // [64][NL] swizzled
    int lane, int wave) {
  constexpr int NS = KL / 64;                // K-steps
  constexpr int WTN = NL / 8;                // 64 (NL=512) or 32 (NL=256)
  constexpr int FN = WTN / 16;               // 4 or 2
  const int n0w = wave * WTN;

  f32x4 acc[4][FN];
#pragma unroll
  for (int i = 0; i < 4; ++i)
#pragma unroll
    for (int j = 0; j < FN; ++j) {
      acc[i][j][0] = 0.f; acc[i][j][1] = 0.f; acc[i][j][2] = 0.f; acc[i][j][3] = 0.f;
    }

  const __hip_bfloat16* wbase =
      Wl + (size_t)(n0w + (lane & 15)) * KL + ((lane >> 4) << 3);

#pragma unroll
  for (int s = 0; s < NS; ++s) {
    s16x8 wf[FN][2];
#pragma unroll
    for (int j = 0; j < FN; ++j)
#pragma unroll
      for (int h = 0; h < 2; ++h)
        wf[j][h] = *(const s16x8*)(wbase + j * 16 * KL + s * 64 + h * 32);
#pragma unroll
    for (int h = 0; h < 2; ++h) {
      int cj = s * 8 + h * 4 + (lane >> 4);  // 16B chunk index within row
#pragma unroll
      for (int i = 0; i < 4; ++i) {
        int ar = i * 16 + (lane & 15);
        int js = cj ^ (ar & 7);
        s16x8 a = *(const s16x8*)(inb + ar * KL + js * 8);
#pragma unroll
        for (int j = 0; j < FN; ++j)
          acc[i][j] = __builtin_amdgcn_mfma_f32_16x16x32_bf16(a, wf[j][h], acc[i][j], 0, 0, 0);
      }
    }
  }

  // epilogue: bias + relu, write straight to outb (different LDS buffer)
  unsigned short* y16 = (unsigned short*)outb;
#pragma unroll
  for (int j = 0; j < FN; ++j) {
    int nc = n0w + j * 16 + (lane & 15);
    float bv = bl[nc];
#pragma unroll
    for (int i = 0; i < 4; ++i) {
#pragma unroll
      for (int r = 0; r < 4; ++r) {
        int mr = i * 16 + ((lane >> 4) << 2) + r;
        float v = acc[i][j][r] + bv;
        if (RELU) v = fmaxf(v, 0.f);
        y16[mr * NL + (((nc >> 3) ^ (mr & 7)) << 3) + (nc & 7)] = bf16bits(v);
      }
    }
  }
  __syncthreads();
}

// layer 7: K=256 -> N=32. 8 waves: wave w owns rows (w&3)*16..+16 and the
// 16-col half (w>>2); f32 output scattered to out[tok][32] via perm.
__device__ __forceinline__ void run_layer7(
    const __hip_bfloat16* __restrict__ W7, const float* __restrict__ b7,
    const __hip_bfloat16* __restrict__ inb, float* __restrict__ out,
    const int* __restrict__ perm, int m0, int lane, int wave) {
  constexpr int KL = 256;
  int rseg = wave & 3, jseg = wave >> 2;
  f32x4 acc;
  acc[0] = 0.f; acc[1] = 0.f; acc[2] = 0.f; acc[3] = 0.f;
  const __hip_bfloat16* wbase =
      W7 + (size_t)(jseg * 16 + (lane & 15)) * KL + ((lane >> 4) << 3);
  int ar = rseg * 16 + (lane & 15);
#pragma unroll
  for (int s = 0; s < 4; ++s) {
#pragma unroll
    for (int h = 0; h < 2; ++h) {
      int kbase = s * 64 + h * 32;
      int cj = (kbase >> 3) + (lane >> 4);
      int js = cj ^ (ar & 7);
      s16x8 a = *(const s16x8*)(inb + ar * KL + js * 8);
      s16x8 w = *(const s16x8*)(wbase + kbase);
      acc = __builtin_amdgcn_mfma_f32_16x16x32_bf16(a, w, acc, 0, 0, 0);
    }
  }
  int nc = jseg * 16 + (lane & 15);
  float bv = b7[nc];
#pragma unroll
  for (int r = 0; r < 4; ++r) {
    int mr = rseg * 16 + ((lane >> 4) << 2) + r;
    int tok = perm[m0 + mr];
    if (tok >= 0) out[(size_t)tok * 32 + nc] = acc[r] + bv;
  }
}

__global__ __attribute__((amdgpu_flat_work_group_size(512, 512),
                          amdgpu_waves_per_eu(2, 2))) void k_fused(
    const __hip_bfloat16* __restrict__ Xs,
    const __hip_bfloat16* __restrict__ W1, const __hip_bfloat16* __restrict__ W2,
    const __hip_bfloat16* __restrict__ W3, const __hip_bfloat16* __restrict__ W4,
    const __hip_bfloat16* __restrict__ W5, const __hip_bfloat16* __restrict__ W6,
    const __hip_bfloat16* __restrict__ W7,
    const float* __restrict__ B1, const float* __restrict__ B2,
    const float* __restrict__ B3, const float* __restrict__ B4,
    const float* __restrict__ B5, const float* __restrict__ B6,
    const float* __restrict__ B7,
    float* __restrict__ out,
    const int* __restrict__ meta, const int* __restrict__ perm) {
  __shared__ __hip_bfloat16 buf0[MROWS * 512];   // 64 KB
  __shared__ __hip_bfloat16 buf1[MROWS * 512];   // 64 KB
  const int* offp = meta + 16;
  int e = blockIdx.x & 7;                     // expert -> XCD affinity
  int s = blockIdx.x >> 3;
  int m0 = offp[e] + s * MROWS;
  if (m0 >= offp[e + 1]) return;
  int tid = threadIdx.x, lane = tid & 63, wave = tid >> 6;

  // stage the 64x128 bf16 input slab (swizzled source, linear LDS dest)
#pragma unroll
  for (int i = 0; i < 2; ++i) {
    int c = i * 512 + tid;
    int r = c >> 4, kc = c & 15;
    int kcs = kc ^ (r & 7);
    gload_lds16(Xs + (size_t)(m0 + r) * 128 + kcs * 8, (char*)buf0 + c * 16);
  }
  asm volatile("s_waitcnt vmcnt(0)" ::: "memory");
  __builtin_amdgcn_s_barrier();

  run_layer<128, 512, true >(W1 + (size_t)e * 512 * 128, B1 + e * 512, buf0, buf1, lane, wave);
  run_layer<512, 512, true >(W2 + (size_t)e * 512 * 512, B2 + e * 512, buf1, buf0, lane, wave);
  run_layer<512, 512, false>(W3 + (size_t)e * 512 * 512, B3 + e * 512, buf0, buf1, lane, wave);
  run_layer<512, 512, true >(W4 + (size_t)e * 512 * 512, B4 + e * 512, buf1, buf0, lane, wave);
  run_layer<512, 512, true >(W5 + (size_t)e * 512 * 512, B5 + e * 512, buf0, buf1, lane, wave);
  run_layer<512, 256, false>(W6 + (size_t)e * 256 * 512, B6 + e * 256, buf1, buf0, lane, wave);
  run_layer7(W7 + (size_t)e * 32 * 256, B7 + e * 32, buf0, out, perm, m0, lane, wave);
}

// ---------------- host ----------------

extern "C" void kernel_launch(void* const* d_in, const int* in_sizes, int n_in,
                              void* d_out, int out_size, void* d_ws, size_t ws_size,
                              hipStream_t stream) {
  const float* input = (const float*)d_in[0];
  const float* Wf[7]; const float* Bf[7];
  for (int i = 0; i < 7; ++i) { Wf[i] = (const float*)d_in[1 + 2 * i]; Bf[i] = (const float*)d_in[2 + 2 * i]; }
  float* out = (float*)d_out;

  static const int NN[7] = {512, 512, 512, 512, 512, 256, 32};
  static const int KK[7] = {128, 512, 512, 512, 512, 512, 256};

  char* ws = (char*)d_ws;
  size_t off = 0;
  auto carve = [&](size_t bytes) {
    void* p = ws + off;
    off = (off + bytes + 255) & ~(size_t)255;
    return p;
  };
  int* meta      = (int*)carve(128);                    // offp at meta[16..24]
  int* ids       = (int*)carve(sizeof(int) * T_TOK);
  int* rowOf     = (int*)carve(sizeof(int) * T_TOK);
  int* perm      = (int*)carve(sizeof(int) * MCAP);
  int* blockHist = (int*)carve(sizeof(int) * NBLK * NEXP);
  int* blockBase = (int*)carve(sizeof(int) * NBLK * NEXP);
  __hip_bfloat16* Xs = (__hip_bfloat16*)carve((size_t)MCAP * 128 * 2);
  __hip_bfloat16* Wb[7];
  for (int i = 0; i < 7; ++i) Wb[i] = (__hip_bfloat16*)carve((size_t)NEXP * NN[i] * KK[i] * 2);

  k_init<<<dim3((MCAP + 255) / 256), 256, 0, stream>>>(perm);
  for (int i = 0; i < 7; ++i) {
    int n4 = NEXP * NN[i] * KK[i] / 4;
    k_w2bf<<<dim3((n4 + 255) / 256), 256, 0, stream>>>(Wf[i], (unsigned long long*)Wb[i], n4);
  }
  k_hist<<<dim3(NBLK), RBLK, 0, stream>>>(input, ids, blockHist);
  k_scan<<<dim3(1), 64, 0, stream>>>(blockHist, blockBase, meta);
  k_assign<<<dim3(NBLK), RBLK, 0, stream>>>(ids, blockBase, rowOf, perm);
  k_gather<<<dim3(T_TOK * 32 / 256), 256, 0, stream>>>(input, rowOf, Xs);
  k_padfill<<<dim3((MCAP + 255) / 256), 256, 0, stream>>>(meta, perm, (unsigned int*)Xs);

  // grid = 8 experts x SLOTS slab slots; inactive slots early-exit.
  // bid&7 = expert -> XCD affinity.
  k_fused<<<dim3(8 * SLOTS), 512, 0, stream>>>(
      Xs, Wb[0], Wb[1], Wb[2], Wb[3], Wb[4], Wb[5], Wb[6],
      Bf[0], Bf[1], Bf[2], Bf[3], Bf[4], Bf[5], Bf[6],
      out, meta, perm);
}